// Round 5
// baseline (4340.936 us; speedup 1.0000x reference)
//
#include <hip/hip_runtime.h>
#include <math.h>

#define DTOK 1222
#define NBOU 80
#define MM   160
#define FFD  2048
#define OQKV 3666

typedef __attribute__((ext_vector_type(8))) short short8;
typedef __attribute__((ext_vector_type(4))) float f32x4;

// ---------- bf16 helpers ----------
__device__ __forceinline__ unsigned short f2bf(float x) {
  unsigned int u = __float_as_uint(x);
  unsigned int r = (u + 0x7FFFu + ((u >> 16) & 1u)) >> 16;
  return (unsigned short)r;
}
__device__ __forceinline__ float bf2f(unsigned short h) {
  return __uint_as_float((unsigned int)h << 16);
}

// ---------- reduction helpers ----------
__device__ __forceinline__ float wave_red_sum(float v) {
#pragma unroll
  for (int off = 32; off; off >>= 1) v += __shfl_xor(v, off, 64);
  return v;
}
__device__ __forceinline__ float block_red_sum(float v, float* rb, int tid) {
  v = wave_red_sum(v);
  __syncthreads();
  if ((tid & 63) == 0) rb[tid >> 6] = v;
  __syncthreads();
  return rb[0] + rb[1] + rb[2] + rb[3];
}

// ---------- zero counters ----------
__global__ __launch_bounds__(256) void k_zero(unsigned int* __restrict__ cnt, int n) {
  for (int i = threadIdx.x; i < n; i += 256) cnt[i] = 0u;
}

// ---------- setup: NCHW -> NHWC full-res transpose ----------
__global__ __launch_bounds__(256) void k_nhwc0(const float* __restrict__ f,
                                               float* __restrict__ L0n) {
  int xt = blockIdx.x;          // 0..6 (32 x each)
  int y  = blockIdx.y;          // 0..223
  int zc = blockIdx.z;          // b*32 + ct
  int b = zc >> 5, ct = zc & 31;
  __shared__ float tile[32][33];
  int tid = threadIdx.x;
  int xl = tid & 31, cl = tid >> 5;
  const float* fb = f + (size_t)b * 1024 * 50176;
#pragma unroll
  for (int i = 0; i < 4; ++i) {
    int c = ct * 32 + cl + i * 8;
    tile[cl + i * 8][xl] = fb[(size_t)c * 50176 + (size_t)y * 224 + xt * 32 + xl];
  }
  __syncthreads();
  int cl2 = tid & 31, xl2 = tid >> 5;
  float* ob = L0n + (((size_t)b * 224 + y) * 224) * 1024;
#pragma unroll
  for (int i = 0; i < 4; ++i) {
    int x = xt * 32 + xl2 + i * 8;
    ob[(size_t)x * 1024 + ct * 32 + cl2] = tile[cl2][xl2 + i * 8];
  }
}

// ---------- setup: pool NHWC -> NHWC (2x2 mean) ----------
__global__ __launch_bounds__(256) void k_pool_nhwc(const float* __restrict__ in,
                                                   float* __restrict__ out, int Ho) {
  int x = blockIdx.x, y = blockIdx.y, b = blockIdx.z;
  int c = threadIdx.x * 4;
  int Hi = Ho * 2;
  const float* p00 = in + (((size_t)(b * Hi + 2 * y) * Hi) + 2 * x) * 1024 + c;
  const float* p01 = p00 + 1024;
  const float* p10 = p00 + (size_t)Hi * 1024;
  const float* p11 = p10 + 1024;
  float4 a = *(const float4*)p00, bv = *(const float4*)p01;
  float4 cv = *(const float4*)p10, dv = *(const float4*)p11;
  float4 r;
  r.x = 0.25f * (a.x + bv.x + cv.x + dv.x);
  r.y = 0.25f * (a.y + bv.y + cv.y + dv.y);
  r.z = 0.25f * (a.z + bv.z + cv.z + dv.z);
  r.w = 0.25f * (a.w + bv.w + cv.w + dv.w);
  *(float4*)(out + (((size_t)(b * Ho + y) * Ho) + x) * 1024 + c) = r;
}

// ---------- setup: positional encoding + boundary init ----------
__global__ __launch_bounds__(256) void k_pe(float* __restrict__ pe, int* __restrict__ bnd,
                                            const int* __restrict__ pb) {
  int n = blockIdx.x, tid = threadIdx.x;
  for (int d = tid; d < DTOK; d += 256) {
    int i = d >> 1;
    double e = exp((double)(2 * i) * (-log(10000.0) / (double)DTOK));
    double ang = (double)n * e;
    pe[n * DTOK + d] = (float)((d & 1) ? cos(ang) : sin(ang));
  }
  if (n == 0) {
    for (int t = tid; t < 2 * NBOU * 2; t += 256) bnd[t] = pb[t];
  }
}

// ---------- weight conversion fp32 [R][K] -> 3-split bf16 frag-linear [RT][T][3][4][64][8] ----------
__global__ __launch_bounds__(256) void k_conv(const float* __restrict__ X,
                                              short* __restrict__ F,
                                              int R, int K, int T) {
  int b = blockIdx.x;
  int rt = b / T, t = b % T;
  int tid = threadIdx.x, mf = tid >> 6, lane = tid & 63;
  int row = rt * 64 + mf * 16 + (lane & 15);
  int k0 = t * 32 + (lane >> 4) * 8;
  float a[8];
#pragma unroll
  for (int j = 0; j < 8; ++j) {
    int k = k0 + j;
    a[j] = (row < R && k < K) ? X[(size_t)row * K + k] : 0.f;
  }
  short8 h, l, q;
#pragma unroll
  for (int j = 0; j < 8; ++j) {
    float x = a[j];
    unsigned short hb = f2bf(x);
    float r1 = x - bf2f(hb);
    unsigned short lb = f2bf(r1);
    float r2 = r1 - bf2f(lb);
    unsigned short qb = f2bf(r2);
    h[j] = (short)hb; l[j] = (short)lb; q[j] = (short)qb;
  }
  size_t base = (size_t)b * 6144 + mf * 512 + (size_t)lane * 8;
  *(short8*)(F + base) = h;
  *(short8*)(F + base + 2048) = l;
  *(short8*)(F + base + 4096) = q;
}

// ---------- per-iteration: token build (all-NHWC gathers) + LN + pe ----------
__global__ __launch_bounds__(256) void k_tok(const float* __restrict__ L0n,
                                             const float* __restrict__ L1,
                                             const float* __restrict__ L2,
                                             const float* __restrict__ L3,
                                             const int* __restrict__ bnd,
                                             const float* __restrict__ g,
                                             const float* __restrict__ bb,
                                             const float* __restrict__ pe,
                                             float* __restrict__ tok_out) {
  int blk = blockIdx.x;
  int b = blk / NBOU, n = blk % NBOU;
  int tid = threadIdx.x, wave = tid >> 6, lane = tid & 63;
  __shared__ __align__(16) float token[1224];
  __shared__ float rbuf[8];
  int bd0 = bnd[blk * 2 + 0], bd1 = bnd[blk * 2 + 1];

  // center feature vector (qf), coalesced
  const float* cp = L0n + (((size_t)b * 224 + bd0) * 224 + bd1) * 1024;
  for (int d = tid * 4; d < 1024; d += 1024) {
    *(float4*)&token[d] = *(const float4*)(cp + d);
  }
  if (tid == 0) { token[1220] = (float)bd0; token[1221] = (float)bd1; }
  __syncthreads();

  // 196 (scale,offset) dot products, wave-per-pair
  for (int p = wave; p < 196; p += 4) {
    int s = p / 49, o = p % 49;
    int Hs = 224 >> s;
    const float* base = (s == 0) ? L0n : (s == 1) ? L1 : (s == 2) ? L2 : L3;
    int yy = (bd0 >> s) + o / 7 - 3;
    int xx = (bd1 >> s) + o % 7 - 3;
    float a = 0.f;
    if (yy >= 0 && yy < Hs && xx >= 0 && xx < Hs) {
      const float* kp = base + (((size_t)b * Hs + yy) * Hs + xx) * 1024;
#pragma unroll
      for (int j = 0; j < 4; ++j) {
        int c = (lane + 64 * j) * 4;
        float4 kv = *(const float4*)(kp + c);
        float4 qv = *(const float4*)(token + c);
        a += kv.x * qv.x + kv.y * qv.y + kv.z * qv.z + kv.w * qv.w;
      }
    }
    a = wave_red_sum(a);
    if (lane == 0) token[1024 + p] = a;
  }
  __syncthreads();

  // LayerNorm + pe
  float ls = 0.f;
  for (int d = tid; d < DTOK; d += 256) ls += token[d];
  float mean = block_red_sum(ls, rbuf, tid) * (1.0f / DTOK);
  float lq = 0.f;
  for (int d = tid; d < DTOK; d += 256) { float t = token[d] - mean; lq += t * t; }
  float var = block_red_sum(lq, rbuf, tid) * (1.0f / DTOK);
  float rstd = rsqrtf(var + 1e-5f);
  for (int d = tid; d < DTOK; d += 256) {
    float o = (token[d] - mean) * rstd * g[d] + bb[d] + pe[n * DTOK + d];
    tok_out[(size_t)blk * DTOK + d] = o;
  }
}

// ---------- barrier-free split-K MFMA GEMM with last-block reduce ----------
// out[160,O] = A[160,K] @ Wfrag^T + bias (+relu) (+res). grid (NT, 3, S).
__global__ __launch_bounds__(256) void k_mfma_sk(const float* __restrict__ A,
                                                 const short* __restrict__ Bf,
                                                 const float* __restrict__ bias,
                                                 const float* __restrict__ res,
                                                 float* __restrict__ out,
                                                 float* __restrict__ partial,
                                                 unsigned int* __restrict__ cnt,
                                                 int K, int T, int O, int S,
                                                 int relu, int NT) {
  int nt = blockIdx.x, mt = blockIdx.y, sp = blockIdx.z;
  int tid = threadIdx.x, w = tid >> 6, lane = tid & 63;
  int wr = w >> 1, wc = w & 1;
  int rl = lane & 15, kq = lane >> 4;
  int cps = (T + S - 1) / S;
  int t0 = sp * cps, t1 = min(t0 + cps, T);

  f32x4 acc[2][2];
#pragma unroll
  for (int mi = 0; mi < 2; ++mi)
#pragma unroll
    for (int ni = 0; ni < 2; ++ni) acc[mi][ni] = (f32x4){0.f, 0.f, 0.f, 0.f};

  const size_t browbase = (size_t)(wc * 2) * 512 + (size_t)lane * 8;

  float av[2][8], av2[2][8];
  short8 bv[3][2], bv2[3][2];

#define LOADSTEP(tt, AV, BV)                                                   \
  {                                                                            \
    int kbase = (tt) * 32 + kq * 8;                                            \
    _Pragma("unroll")                                                          \
    for (int mi = 0; mi < 2; ++mi) {                                           \
      int r = mt * 64 + wr * 32 + mi * 16 + rl;                                \
      const float* ap = A + (size_t)r * K + kbase;                             \
      bool rv = r < MM;                                                        \
      _Pragma("unroll")                                                        \
      for (int j = 0; j < 8; ++j)                                              \
        AV[mi][j] = (rv && (kbase + j) < K) ? ap[j] : 0.f;                     \
    }                                                                          \
    const short* bp = Bf + ((size_t)nt * T + (tt)) * 6144 + browbase;          \
    _Pragma("unroll")                                                          \
    for (int s = 0; s < 3; ++s) {                                              \
      _Pragma("unroll")                                                        \
      for (int ni = 0; ni < 2; ++ni)                                           \
        BV[s][ni] = *(const short8*)(bp + s * 2048 + ni * 512);                \
    }                                                                          \
  }

  if (t0 < t1) {
    LOADSTEP(t0, av, bv);
    for (int t = t0; t < t1; ++t) {
      if (t + 1 < t1) LOADSTEP(t + 1, av2, bv2);
      short8 ah[2], al[2], aq[2];
#pragma unroll
      for (int mi = 0; mi < 2; ++mi)
#pragma unroll
        for (int j = 0; j < 8; ++j) {
          float x = av[mi][j];
          unsigned short hb = f2bf(x);
          float r1 = x - bf2f(hb);
          unsigned short lb = f2bf(r1);
          float r2 = r1 - bf2f(lb);
          ah[mi][j] = (short)hb;
          al[mi][j] = (short)lb;
          aq[mi][j] = (short)f2bf(r2);
        }
#pragma unroll
      for (int mi = 0; mi < 2; ++mi)
#pragma unroll
        for (int ni = 0; ni < 2; ++ni) {
          f32x4 a = acc[mi][ni];
          a = __builtin_amdgcn_mfma_f32_16x16x32_bf16(ah[mi], bv[0][ni], a, 0, 0, 0); // hh
          a = __builtin_amdgcn_mfma_f32_16x16x32_bf16(ah[mi], bv[1][ni], a, 0, 0, 0); // hl
          a = __builtin_amdgcn_mfma_f32_16x16x32_bf16(al[mi], bv[0][ni], a, 0, 0, 0); // lh
          a = __builtin_amdgcn_mfma_f32_16x16x32_bf16(ah[mi], bv[2][ni], a, 0, 0, 0); // h3
          a = __builtin_amdgcn_mfma_f32_16x16x32_bf16(aq[mi], bv[0][ni], a, 0, 0, 0); // 3h
          a = __builtin_amdgcn_mfma_f32_16x16x32_bf16(al[mi], bv[1][ni], a, 0, 0, 0); // ll
          acc[mi][ni] = a;
        }
#pragma unroll
      for (int mi = 0; mi < 2; ++mi)
#pragma unroll
        for (int j = 0; j < 8; ++j) av[mi][j] = av2[mi][j];
#pragma unroll
      for (int s = 0; s < 3; ++s)
#pragma unroll
        for (int ni = 0; ni < 2; ++ni) bv[s][ni] = bv2[s][ni];
    }
  }
#undef LOADSTEP

  // write this split's partial
  float* pp = partial + (size_t)sp * MM * O;
#pragma unroll
  for (int mi = 0; mi < 2; ++mi)
#pragma unroll
    for (int ni = 0; ni < 2; ++ni) {
      int c = nt * 64 + wc * 32 + ni * 16 + rl;
      if (c >= O) continue;
#pragma unroll
      for (int reg = 0; reg < 4; ++reg) {
        int r = mt * 64 + wr * 32 + mi * 16 + kq * 4 + reg;
        if (r < MM) pp[(size_t)r * O + c] = acc[mi][ni][reg];
      }
    }

  __threadfence();
  __shared__ unsigned int done;
  if (tid == 0) done = atomicAdd(&cnt[mt * NT + nt], 1u);
  __syncthreads();
  if (done == (unsigned)(S - 1)) {
    __threadfence();
    int c = nt * 64 + (tid & 63);
    if (c < O) {
      for (int rr2 = tid >> 6; rr2 < 64; rr2 += 4) {
        int r = mt * 64 + rr2;
        if (r >= MM) break;
        float v = 0.f;
        for (int s2 = 0; s2 < S; ++s2) v += partial[((size_t)s2 * MM + r) * O + c];
        v += bias[c];
        if (relu) v = fmaxf(v, 0.f);
        if (res) v += res[(size_t)r * O + c];
        out[(size_t)r * O + c] = v;
      }
    }
  }
}

// ---------- attention (per (b,n) row) ----------
__global__ __launch_bounds__(256) void k_attn(const float* __restrict__ qkv,
                                              float* __restrict__ attn_out) {
  int blk = blockIdx.x;
  int b = blk / NBOU;
  int tid = threadIdx.x, wave = tid >> 6, lane = tid & 63;
  __shared__ float p[80];
  float qr[20];
  const float* qrow = qkv + (size_t)blk * OQKV;
#pragma unroll
  for (int j = 0; j < 20; ++j) {
    int d = lane + 64 * j;
    qr[j] = (d < DTOK) ? qrow[d] : 0.f;
  }
  for (int m2 = wave; m2 < 80; m2 += 4) {
    const float* krow = qkv + (size_t)(b * NBOU + m2) * OQKV + DTOK;
    float a = 0.f;
#pragma unroll
    for (int j = 0; j < 20; ++j) {
      int d = lane + 64 * j;
      if (d < DTOK) a += qr[j] * krow[d];
    }
    a = wave_red_sum(a);
    if (lane == 0) p[m2] = a * (1.0f / 34.957116f);
  }
  __syncthreads();
  if (wave == 0) {
    float x0 = p[lane];
    float x1 = (lane < 16) ? p[64 + lane] : -INFINITY;
    float mx = fmaxf(x0, x1);
#pragma unroll
    for (int off = 32; off; off >>= 1) mx = fmaxf(mx, __shfl_xor(mx, off, 64));
    float e0 = expf(x0 - mx);
    float e1 = (lane < 16) ? expf(x1 - mx) : 0.f;
    float ssum = wave_red_sum(e0 + e1);
    p[lane] = e0 / ssum;
    if (lane < 16) p[64 + lane] = e1 / ssum;
  }
  __syncthreads();
  float acc[5] = {0, 0, 0, 0, 0};
  for (int m2 = 0; m2 < 80; ++m2) {
    float pm = p[m2];
    const float* vrow = qkv + (size_t)(b * NBOU + m2) * OQKV + 2 * DTOK;
#pragma unroll
    for (int i = 0; i < 5; ++i) {
      int d = tid + 256 * i;
      if (d < DTOK) acc[i] += pm * vrow[d];
    }
  }
#pragma unroll
  for (int i = 0; i < 5; ++i) {
    int d = tid + 256 * i;
    if (d < DTOK) attn_out[(size_t)blk * DTOK + d] = acc[i];
  }
}

// ---------- LayerNorm ----------
__global__ __launch_bounds__(256) void k_ln(const float* __restrict__ xin,
                                            const float* __restrict__ g,
                                            const float* __restrict__ bb,
                                            float* __restrict__ xout) {
  int m = blockIdx.x, tid = threadIdx.x;
  __shared__ float row[DTOK];
  __shared__ float rb[8];
  const float* xr = xin + (size_t)m * DTOK;
  float ls = 0.f;
  for (int d = tid; d < DTOK; d += 256) { float v = xr[d]; row[d] = v; ls += v; }
  float mean = block_red_sum(ls, rb, tid) * (1.0f / DTOK);
  float lq = 0.f;
  for (int d = tid; d < DTOK; d += 256) { float t = row[d] - mean; lq += t * t; }
  float var = block_red_sum(lq, rb, tid) * (1.0f / DTOK);
  float rstd = rsqrtf(var + 1e-5f);
  for (int d = tid; d < DTOK; d += 256)
    xout[(size_t)m * DTOK + d] = (row[d] - mean) * rstd * g[d] + bb[d];
}

// ---------- fused norm2-LN + fc head + boundary update ----------
__global__ __launch_bounds__(256) void k_lnfc(const float* __restrict__ xin,
                                              const float* __restrict__ g,
                                              const float* __restrict__ bb,
                                              const float* __restrict__ fcw,
                                              const float* __restrict__ fcb,
                                              int* __restrict__ bnd,
                                              int* __restrict__ outp) {
  int blk = blockIdx.x;
  int n = blk % NBOU;
  int tid = threadIdx.x;
  __shared__ float row[DTOK];
  __shared__ float rb[8];
  const float* xr = xin + (size_t)blk * DTOK;
  float ls = 0.f;
  for (int d = tid; d < DTOK; d += 256) { float v = xr[d]; row[d] = v; ls += v; }
  float mean = block_red_sum(ls, rb, tid) * (1.0f / DTOK);
  float lq = 0.f;
  for (int d = tid; d < DTOK; d += 256) { float t = row[d] - mean; lq += t * t; }
  float var = block_red_sum(lq, rb, tid) * (1.0f / DTOK);
  float rstd = rsqrtf(var + 1e-5f);
  const float* w0 = fcw + (size_t)n * 1026 * DTOK;
  const float* w1 = w0 + DTOK;
  float s0 = 0.f, s1 = 0.f;
  for (int d = tid; d < DTOK; d += 256) {
    float xn = (row[d] - mean) * rstd * g[d] + bb[d];
    s0 += xn * w0[d];
    s1 += xn * w1[d];
  }
  s0 = block_red_sum(s0, rb, tid);
  s1 = block_red_sum(s1, rb, tid);
  if (tid == 0) {
    float o0 = s0 + fcb[n * 1026 + 0];
    float o1 = s1 + fcb[n * 1026 + 1];
    int b0 = bnd[blk * 2 + 0], b1 = bnd[blk * 2 + 1];
    int nb0 = b0 + (int)truncf(o0);
    int nb1 = b1 + (int)truncf(o1);
    nb0 = nb0 < 0 ? 0 : (nb0 > 223 ? 223 : nb0);
    nb1 = nb1 < 0 ? 0 : (nb1 > 223 ? 223 : nb1);
    bnd[blk * 2 + 0] = nb0;
    bnd[blk * 2 + 1] = nb1;
    outp[blk * 2 + 0] = nb0;
    outp[blk * 2 + 1] = nb1;
  }
}

extern "C" void kernel_launch(void* const* d_in, const int* in_sizes, int n_in,
                              void* d_out, int out_size, void* d_ws, size_t ws_size,
                              hipStream_t stream) {
  const float* f   = (const float*)d_in[0];
  const int*   pb  = (const int*)d_in[1];
  const float* lng = (const float*)d_in[2];
  const float* lnb = (const float*)d_in[3];
  const float* ipw = (const float*)d_in[4];
  const float* ipb = (const float*)d_in[5];
  const float* opw = (const float*)d_in[6];
  const float* opb = (const float*)d_in[7];
  const float* l1w = (const float*)d_in[8];
  const float* l1b = (const float*)d_in[9];
  const float* l2w = (const float*)d_in[10];
  const float* l2b = (const float*)d_in[11];
  const float* n1g = (const float*)d_in[12];
  const float* n1b = (const float*)d_in[13];
  const float* n2g = (const float*)d_in[14];
  const float* n2b = (const float*)d_in[15];
  const float* fcw = (const float*)d_in[16];
  const float* fcb = (const float*)d_in[17];
  int* outp = (int*)d_out;

  const int T1 = 39;   // ceil(1222/32)
  const int T2 = 64;   // 2048/32
  const int NT_IP = 58, NT_OP = 20, NT_L1 = 32, NT_L2 = 20;
  const int S_IP = 4, S_OP = 6, S_L1 = 4, S_L2 = 6;
  // counters per iteration: ip 174, op 60, l1 96, l2 60 = 390
  const int CNT_PER_IT = 174 + 60 + 96 + 60;

  char* wsb = (char*)d_ws;
  auto alloc = [&](size_t bytes) -> char* {
    char* p = wsb;
    wsb += (bytes + 255) & ~(size_t)255;
    return p;
  };
  float* L0n  = (float*)alloc((size_t)2 * 224 * 224 * 1024 * 4);
  float* L1   = (float*)alloc((size_t)2 * 112 * 112 * 1024 * 4);
  float* L2   = (float*)alloc((size_t)2 * 56 * 56 * 1024 * 4);
  float* L3   = (float*)alloc((size_t)2 * 28 * 28 * 1024 * 4);
  float* pe   = (float*)alloc((size_t)NBOU * DTOK * 4);
  int*   bnd  = (int*)alloc(320 * 4);
  float* tokens = (float*)alloc((size_t)MM * DTOK * 4);
  float* qkvb   = (float*)alloc((size_t)MM * OQKV * 4);
  float* attnb  = (float*)alloc((size_t)MM * DTOK * 4);
  float* x1pre  = (float*)alloc((size_t)MM * DTOK * 4);
  float* x1     = (float*)alloc((size_t)MM * DTOK * 4);
  float* hb     = (float*)alloc((size_t)MM * FFD * 4);
  float* x2pre  = (float*)alloc((size_t)MM * DTOK * 4);
  short* ipWf = (short*)alloc((size_t)NT_IP * T1 * 6144 * 2);
  short* opWf = (short*)alloc((size_t)NT_OP * T1 * 6144 * 2);
  short* l1Wf = (short*)alloc((size_t)NT_L1 * T1 * 6144 * 2);
  short* l2Wf = (short*)alloc((size_t)NT_L2 * T2 * 6144 * 2);
  float* part = (float*)alloc((size_t)6 * MM * OQKV * 4);
  unsigned int* cnt = (unsigned int*)alloc((size_t)6 * CNT_PER_IT * 4);

  k_zero<<<1, 256, 0, stream>>>(cnt, 6 * CNT_PER_IT);
  k_nhwc0<<<dim3(7, 224, 64), 256, 0, stream>>>(f, L0n);
  k_pool_nhwc<<<dim3(112, 112, 2), 256, 0, stream>>>(L0n, L1, 112);
  k_pool_nhwc<<<dim3(56, 56, 2), 256, 0, stream>>>(L1, L2, 56);
  k_pool_nhwc<<<dim3(28, 28, 2), 256, 0, stream>>>(L2, L3, 28);
  k_pe<<<NBOU, 256, 0, stream>>>(pe, bnd, pb);

  k_conv<<<NT_IP * T1, 256, 0, stream>>>(ipw, ipWf, OQKV, DTOK, T1);
  k_conv<<<NT_OP * T1, 256, 0, stream>>>(opw, opWf, DTOK, DTOK, T1);
  k_conv<<<NT_L1 * T1, 256, 0, stream>>>(l1w, l1Wf, FFD, DTOK, T1);
  k_conv<<<NT_L2 * T2, 256, 0, stream>>>(l2w, l2Wf, DTOK, FFD, T2);

  for (int it = 0; it < 6; ++it) {
    unsigned int* cit = cnt + (size_t)it * CNT_PER_IT;

    k_tok<<<160, 256, 0, stream>>>(L0n, L1, L2, L3, bnd, lng, lnb, pe, tokens);

    k_mfma_sk<<<dim3(NT_IP, 3, S_IP), 256, 0, stream>>>(
        tokens, ipWf, ipb, nullptr, qkvb, part, cit, DTOK, T1, OQKV, S_IP, 0, NT_IP);

    k_attn<<<160, 256, 0, stream>>>(qkvb, attnb);

    k_mfma_sk<<<dim3(NT_OP, 3, S_OP), 256, 0, stream>>>(
        attnb, opWf, opb, tokens, x1pre, part, cit + 174, DTOK, T1, DTOK, S_OP, 0, NT_OP);

    k_ln<<<160, 256, 0, stream>>>(x1pre, n1g, n1b, x1);

    k_mfma_sk<<<dim3(NT_L1, 3, S_L1), 256, 0, stream>>>(
        x1, l1Wf, l1b, nullptr, hb, part, cit + 234, DTOK, T1, FFD, S_L1, 1, NT_L1);

    k_mfma_sk<<<dim3(NT_L2, 3, S_L2), 256, 0, stream>>>(
        hb, l2Wf, l2b, x1, x2pre, part, cit + 330, FFD, T2, DTOK, S_L2, 0, NT_L2);

    k_lnfc<<<160, 256, 0, stream>>>(x2pre, n2g, n2b, fcw, fcb, bnd, outp + it * 320);
  }
}

// Round 6
// 2005.941 us; speedup vs baseline: 2.1640x; 2.1640x over previous
//
#include <hip/hip_runtime.h>
#include <math.h>

#define DTOK 1222
#define NBOU 80
#define MM   160
#define FFD  2048
#define OQKV 3666

typedef __attribute__((ext_vector_type(8))) short short8;
typedef __attribute__((ext_vector_type(4))) float f32x4;

// ---------- bf16 helpers ----------
__device__ __forceinline__ unsigned short f2bf(float x) {
  unsigned int u = __float_as_uint(x);
  unsigned int r = (u + 0x7FFFu + ((u >> 16) & 1u)) >> 16;
  return (unsigned short)r;
}
__device__ __forceinline__ float bf2f(unsigned short h) {
  return __uint_as_float((unsigned int)h << 16);
}

// ---------- reduction helpers ----------
__device__ __forceinline__ float wave_red_sum(float v) {
#pragma unroll
  for (int off = 32; off; off >>= 1) v += __shfl_xor(v, off, 64);
  return v;
}
__device__ __forceinline__ float block_red_sum(float v, float* rb, int tid) {
  v = wave_red_sum(v);
  __syncthreads();
  if ((tid & 63) == 0) rb[tid >> 6] = v;
  __syncthreads();
  return rb[0] + rb[1] + rb[2] + rb[3];
}

// ---------- setup: NCHW -> NHWC full-res transpose ----------
__global__ __launch_bounds__(256) void k_nhwc0(const float* __restrict__ f,
                                               float* __restrict__ L0n) {
  int xt = blockIdx.x;          // 0..6 (32 x each)
  int y  = blockIdx.y;          // 0..223
  int zc = blockIdx.z;          // b*32 + ct
  int b = zc >> 5, ct = zc & 31;
  __shared__ float tile[32][33];
  int tid = threadIdx.x;
  int xl = tid & 31, cl = tid >> 5;
  const float* fb = f + (size_t)b * 1024 * 50176;
#pragma unroll
  for (int i = 0; i < 4; ++i) {
    int c = ct * 32 + cl + i * 8;
    tile[cl + i * 8][xl] = fb[(size_t)c * 50176 + (size_t)y * 224 + xt * 32 + xl];
  }
  __syncthreads();
  int cl2 = tid & 31, xl2 = tid >> 5;
  float* ob = L0n + (((size_t)b * 224 + y) * 224) * 1024;
#pragma unroll
  for (int i = 0; i < 4; ++i) {
    int x = xt * 32 + xl2 + i * 8;
    ob[(size_t)x * 1024 + ct * 32 + cl2] = tile[cl2][xl2 + i * 8];
  }
}

// ---------- setup: pool NHWC -> NHWC (2x2 mean) ----------
__global__ __launch_bounds__(256) void k_pool_nhwc(const float* __restrict__ in,
                                                   float* __restrict__ out, int Ho) {
  int x = blockIdx.x, y = blockIdx.y, b = blockIdx.z;
  int c = threadIdx.x * 4;
  int Hi = Ho * 2;
  const float* p00 = in + (((size_t)(b * Hi + 2 * y) * Hi) + 2 * x) * 1024 + c;
  const float* p01 = p00 + 1024;
  const float* p10 = p00 + (size_t)Hi * 1024;
  const float* p11 = p10 + 1024;
  float4 a = *(const float4*)p00, bv = *(const float4*)p01;
  float4 cv = *(const float4*)p10, dv = *(const float4*)p11;
  float4 r;
  r.x = 0.25f * (a.x + bv.x + cv.x + dv.x);
  r.y = 0.25f * (a.y + bv.y + cv.y + dv.y);
  r.z = 0.25f * (a.z + bv.z + cv.z + dv.z);
  r.w = 0.25f * (a.w + bv.w + cv.w + dv.w);
  *(float4*)(out + (((size_t)(b * Ho + y) * Ho) + x) * 1024 + c) = r;
}

// ---------- setup: positional encoding + boundary init ----------
__global__ __launch_bounds__(256) void k_pe(float* __restrict__ pe, int* __restrict__ bnd,
                                            const int* __restrict__ pb) {
  int n = blockIdx.x, tid = threadIdx.x;
  for (int d = tid; d < DTOK; d += 256) {
    int i = d >> 1;
    double e = exp((double)(2 * i) * (-log(10000.0) / (double)DTOK));
    double ang = (double)n * e;
    pe[n * DTOK + d] = (float)((d & 1) ? cos(ang) : sin(ang));
  }
  if (n == 0) {
    for (int t = tid; t < 2 * NBOU * 2; t += 256) bnd[t] = pb[t];
  }
}

// ---------- weight conversion fp32 [R][K] -> 3-split bf16 frag-linear [RT][T][3][4][64][8] ----------
__global__ __launch_bounds__(256) void k_conv(const float* __restrict__ X,
                                              short* __restrict__ F,
                                              int R, int K, int T) {
  int b = blockIdx.x;
  int rt = b / T, t = b % T;
  int tid = threadIdx.x, mf = tid >> 6, lane = tid & 63;
  int row = rt * 64 + mf * 16 + (lane & 15);
  int k0 = t * 32 + (lane >> 4) * 8;
  float a[8];
#pragma unroll
  for (int j = 0; j < 8; ++j) {
    int k = k0 + j;
    a[j] = (row < R && k < K) ? X[(size_t)row * K + k] : 0.f;
  }
  short8 h, l, q;
#pragma unroll
  for (int j = 0; j < 8; ++j) {
    float x = a[j];
    unsigned short hb = f2bf(x);
    float r1 = x - bf2f(hb);
    unsigned short lb = f2bf(r1);
    float r2 = r1 - bf2f(lb);
    unsigned short qb = f2bf(r2);
    h[j] = (short)hb; l[j] = (short)lb; q[j] = (short)qb;
  }
  size_t base = (size_t)b * 6144 + mf * 512 + (size_t)lane * 8;
  *(short8*)(F + base) = h;
  *(short8*)(F + base + 2048) = l;
  *(short8*)(F + base + 4096) = q;
}

// ---------- per-iteration: token build (all-NHWC gathers) + LN + pe ----------
__global__ __launch_bounds__(256) void k_tok(const float* __restrict__ L0n,
                                             const float* __restrict__ L1,
                                             const float* __restrict__ L2,
                                             const float* __restrict__ L3,
                                             const int* __restrict__ bnd,
                                             const float* __restrict__ g,
                                             const float* __restrict__ bb,
                                             const float* __restrict__ pe,
                                             float* __restrict__ tok_out) {
  int blk = blockIdx.x;
  int b = blk / NBOU, n = blk % NBOU;
  int tid = threadIdx.x, wave = tid >> 6, lane = tid & 63;
  __shared__ __align__(16) float token[1224];
  __shared__ float rbuf[8];
  int bd0 = bnd[blk * 2 + 0], bd1 = bnd[blk * 2 + 1];

  const float* cp = L0n + (((size_t)b * 224 + bd0) * 224 + bd1) * 1024;
  {
    int d = tid * 4;
    *(float4*)&token[d] = *(const float4*)(cp + d);
  }
  if (tid == 0) { token[1220] = (float)bd0; token[1221] = (float)bd1; }
  __syncthreads();

  for (int p = wave; p < 196; p += 4) {
    int s = p / 49, o = p % 49;
    int Hs = 224 >> s;
    const float* base = (s == 0) ? L0n : (s == 1) ? L1 : (s == 2) ? L2 : L3;
    int yy = (bd0 >> s) + o / 7 - 3;
    int xx = (bd1 >> s) + o % 7 - 3;
    float a = 0.f;
    if (yy >= 0 && yy < Hs && xx >= 0 && xx < Hs) {
      const float* kp = base + (((size_t)b * Hs + yy) * Hs + xx) * 1024;
#pragma unroll
      for (int j = 0; j < 4; ++j) {
        int c = (lane + 64 * j) * 4;
        float4 kv = *(const float4*)(kp + c);
        float4 qv = *(const float4*)(token + c);
        a += kv.x * qv.x + kv.y * qv.y + kv.z * qv.z + kv.w * qv.w;
      }
    }
    a = wave_red_sum(a);
    if (lane == 0) token[1024 + p] = a;
  }
  __syncthreads();

  float ls = 0.f;
  for (int d = tid; d < DTOK; d += 256) ls += token[d];
  float mean = block_red_sum(ls, rbuf, tid) * (1.0f / DTOK);
  float lq = 0.f;
  for (int d = tid; d < DTOK; d += 256) { float t = token[d] - mean; lq += t * t; }
  float var = block_red_sum(lq, rbuf, tid) * (1.0f / DTOK);
  float rstd = rsqrtf(var + 1e-5f);
  for (int d = tid; d < DTOK; d += 256) {
    float o = (token[d] - mean) * rstd * g[d] + bb[d] + pe[n * DTOK + d];
    tok_out[(size_t)blk * DTOK + d] = o;
  }
}

// ---------- split-K MFMA GEMM, partial writer only (no fence/atomic/tail) ----------
// partial[sp][160][O] = A[160, Kslice] @ Wfrag^T. grid (NT, 3, S).
__global__ __launch_bounds__(256) void k_mfma_s(const float* __restrict__ A,
                                                const short* __restrict__ Bf,
                                                float* __restrict__ partial,
                                                int K, int T, int O, int S) {
  int nt = blockIdx.x, mt = blockIdx.y, sp = blockIdx.z;
  int tid = threadIdx.x, w = tid >> 6, lane = tid & 63;
  int wr = w >> 1, wc = w & 1;
  int rl = lane & 15, kq = lane >> 4;
  int cps = (T + S - 1) / S;
  int t0 = sp * cps, t1 = min(t0 + cps, T);

  f32x4 acc[2][2];
#pragma unroll
  for (int mi = 0; mi < 2; ++mi)
#pragma unroll
    for (int ni = 0; ni < 2; ++ni) acc[mi][ni] = (f32x4){0.f, 0.f, 0.f, 0.f};

  const size_t browbase = (size_t)(wc * 2) * 512 + (size_t)lane * 8;

  float av[2][8], av2[2][8];
  short8 bv[3][2], bv2[3][2];

#define LOADSTEP(tt, AV, BV)                                                   \
  {                                                                            \
    int kbase = (tt) * 32 + kq * 8;                                            \
    _Pragma("unroll")                                                          \
    for (int mi = 0; mi < 2; ++mi) {                                           \
      int r = mt * 64 + wr * 32 + mi * 16 + rl;                                \
      const float* ap = A + (size_t)r * K + kbase;                             \
      if (r < MM && kbase + 8 <= K) {                                          \
        _Pragma("unroll")                                                      \
        for (int j2 = 0; j2 < 4; ++j2) {                                       \
          float2 v = *(const float2*)(ap + j2 * 2);                            \
          AV[mi][j2 * 2] = v.x; AV[mi][j2 * 2 + 1] = v.y;                      \
        }                                                                      \
      } else {                                                                 \
        bool rv = r < MM;                                                      \
        _Pragma("unroll")                                                      \
        for (int j = 0; j < 8; ++j)                                            \
          AV[mi][j] = (rv && (kbase + j) < K) ? ap[j] : 0.f;                   \
      }                                                                        \
    }                                                                          \
    const short* bp = Bf + ((size_t)nt * T + (tt)) * 6144 + browbase;          \
    _Pragma("unroll")                                                          \
    for (int s = 0; s < 3; ++s) {                                              \
      _Pragma("unroll")                                                        \
      for (int ni = 0; ni < 2; ++ni)                                           \
        BV[s][ni] = *(const short8*)(bp + s * 2048 + ni * 512);                \
    }                                                                          \
  }

  if (t0 < t1) {
    LOADSTEP(t0, av, bv);
    for (int t = t0; t < t1; ++t) {
      if (t + 1 < t1) LOADSTEP(t + 1, av2, bv2);
      short8 ah[2], al[2], aq[2];
#pragma unroll
      for (int mi = 0; mi < 2; ++mi)
#pragma unroll
        for (int j = 0; j < 8; ++j) {
          float x = av[mi][j];
          unsigned short hb = f2bf(x);
          float r1 = x - bf2f(hb);
          unsigned short lb = f2bf(r1);
          float r2 = r1 - bf2f(lb);
          ah[mi][j] = (short)hb;
          al[mi][j] = (short)lb;
          aq[mi][j] = (short)f2bf(r2);
        }
#pragma unroll
      for (int mi = 0; mi < 2; ++mi)
#pragma unroll
        for (int ni = 0; ni < 2; ++ni) {
          f32x4 a = acc[mi][ni];
          a = __builtin_amdgcn_mfma_f32_16x16x32_bf16(ah[mi], bv[0][ni], a, 0, 0, 0); // hh
          a = __builtin_amdgcn_mfma_f32_16x16x32_bf16(ah[mi], bv[1][ni], a, 0, 0, 0); // hl
          a = __builtin_amdgcn_mfma_f32_16x16x32_bf16(al[mi], bv[0][ni], a, 0, 0, 0); // lh
          a = __builtin_amdgcn_mfma_f32_16x16x32_bf16(ah[mi], bv[2][ni], a, 0, 0, 0); // h3
          a = __builtin_amdgcn_mfma_f32_16x16x32_bf16(aq[mi], bv[0][ni], a, 0, 0, 0); // 3h
          a = __builtin_amdgcn_mfma_f32_16x16x32_bf16(al[mi], bv[1][ni], a, 0, 0, 0); // ll
          acc[mi][ni] = a;
        }
#pragma unroll
      for (int mi = 0; mi < 2; ++mi)
#pragma unroll
        for (int j = 0; j < 8; ++j) av[mi][j] = av2[mi][j];
#pragma unroll
      for (int s = 0; s < 3; ++s)
#pragma unroll
        for (int ni = 0; ni < 2; ++ni) bv[s][ni] = bv2[s][ni];
    }
  }
#undef LOADSTEP

  float* pp = partial + (size_t)sp * MM * O;
#pragma unroll
  for (int mi = 0; mi < 2; ++mi)
#pragma unroll
    for (int ni = 0; ni < 2; ++ni) {
      int c = nt * 64 + wc * 32 + ni * 16 + rl;
      if (c >= O) continue;
#pragma unroll
      for (int reg = 0; reg < 4; ++reg) {
        int r = mt * 64 + wr * 32 + mi * 16 + kq * 4 + reg;
        if (r < MM) pp[(size_t)r * O + c] = acc[mi][ni][reg];
      }
    }
}

// ---------- parallel split-K reduce + bias (+relu)(+res) ----------
__global__ __launch_bounds__(256) void k_red(const float* __restrict__ partial,
                                             const float* __restrict__ bias,
                                             const float* __restrict__ res,
                                             float* __restrict__ out,
                                             int O, int S, int relu) {
  size_t idx = ((size_t)blockIdx.x * 256 + threadIdx.x) * 4;
  size_t total = (size_t)MM * O;
  if (idx >= total) return;
  float4 v = *(const float4*)(partial + idx);
  for (int s = 1; s < S; ++s) {
    float4 p = *(const float4*)(partial + (size_t)s * total + idx);
    v.x += p.x; v.y += p.y; v.z += p.z; v.w += p.w;
  }
  float r[4] = {v.x, v.y, v.z, v.w};
#pragma unroll
  for (int j = 0; j < 4; ++j) {
    int o = (int)((idx + j) % O);
    r[j] += bias[o];
    if (relu) r[j] = fmaxf(r[j], 0.f);
  }
  if (res) {
    float4 q = *(const float4*)(res + idx);
    r[0] += q.x; r[1] += q.y; r[2] += q.z; r[3] += q.w;
  }
  float4 wv = {r[0], r[1], r[2], r[3]};
  *(float4*)(out + idx) = wv;
}

// ---------- fused: split-K reduce + bias + residual + LayerNorm -> xout ----------
__global__ __launch_bounds__(256) void k_redln(const float* __restrict__ partial,
                                               const float* __restrict__ bias,
                                               const float* __restrict__ res,
                                               const float* __restrict__ g,
                                               const float* __restrict__ bb,
                                               float* __restrict__ xout,
                                               int S) {
  const int O = DTOK;
  int m = blockIdx.x, tid = threadIdx.x;
  __shared__ float row[DTOK];
  __shared__ float rb[8];
  float ls = 0.f;
  for (int d = tid; d < O; d += 256) {
    float v = 0.f;
    for (int s = 0; s < S; ++s) v += partial[((size_t)s * MM + m) * O + d];
    v += bias[d];
    v += res[(size_t)m * O + d];
    row[d] = v; ls += v;
  }
  float mean = block_red_sum(ls, rb, tid) * (1.0f / DTOK);
  float lq = 0.f;
  for (int d = tid; d < O; d += 256) { float t = row[d] - mean; lq += t * t; }
  float var = block_red_sum(lq, rb, tid) * (1.0f / DTOK);
  float rstd = rsqrtf(var + 1e-5f);
  for (int d = tid; d < O; d += 256)
    xout[(size_t)m * O + d] = (row[d] - mean) * rstd * g[d] + bb[d];
}

// ---------- fused: split-K reduce + bias + residual + LN + fc head + boundary update ----------
__global__ __launch_bounds__(256) void k_redlnfc(const float* __restrict__ partial,
                                                 const float* __restrict__ bias,
                                                 const float* __restrict__ res,
                                                 const float* __restrict__ g,
                                                 const float* __restrict__ bb,
                                                 const float* __restrict__ fcw,
                                                 const float* __restrict__ fcb,
                                                 int* __restrict__ bnd,
                                                 int* __restrict__ outp,
                                                 int S) {
  const int O = DTOK;
  int blk = blockIdx.x;
  int n = blk % NBOU;
  int tid = threadIdx.x;
  __shared__ float row[DTOK];
  __shared__ float rb[8];
  float ls = 0.f;
  for (int d = tid; d < O; d += 256) {
    float v = 0.f;
    for (int s = 0; s < S; ++s) v += partial[((size_t)s * MM + blk) * O + d];
    v += bias[d];
    v += res[(size_t)blk * O + d];
    row[d] = v; ls += v;
  }
  float mean = block_red_sum(ls, rb, tid) * (1.0f / DTOK);
  float lq = 0.f;
  for (int d = tid; d < O; d += 256) { float t = row[d] - mean; lq += t * t; }
  float var = block_red_sum(lq, rb, tid) * (1.0f / DTOK);
  float rstd = rsqrtf(var + 1e-5f);
  const float* w0 = fcw + (size_t)n * 1026 * DTOK;
  const float* w1 = w0 + DTOK;
  float s0 = 0.f, s1 = 0.f;
  for (int d = tid; d < O; d += 256) {
    float xn = (row[d] - mean) * rstd * g[d] + bb[d];
    s0 += xn * w0[d];
    s1 += xn * w1[d];
  }
  s0 = block_red_sum(s0, rb, tid);
  s1 = block_red_sum(s1, rb, tid);
  if (tid == 0) {
    float o0 = s0 + fcb[n * 1026 + 0];
    float o1 = s1 + fcb[n * 1026 + 1];
    int b0 = bnd[blk * 2 + 0], b1 = bnd[blk * 2 + 1];
    int nb0 = b0 + (int)truncf(o0);
    int nb1 = b1 + (int)truncf(o1);
    nb0 = nb0 < 0 ? 0 : (nb0 > 223 ? 223 : nb0);
    nb1 = nb1 < 0 ? 0 : (nb1 > 223 ? 223 : nb1);
    bnd[blk * 2 + 0] = nb0;
    bnd[blk * 2 + 1] = nb1;
    outp[blk * 2 + 0] = nb0;
    outp[blk * 2 + 1] = nb1;
  }
}

// ---------- attention (per (b,n) row) ----------
__global__ __launch_bounds__(256) void k_attn(const float* __restrict__ qkv,
                                              float* __restrict__ attn_out) {
  int blk = blockIdx.x;
  int b = blk / NBOU;
  int tid = threadIdx.x, wave = tid >> 6, lane = tid & 63;
  __shared__ float p[80];
  float qr[20];
  const float* qrow = qkv + (size_t)blk * OQKV;
#pragma unroll
  for (int j = 0; j < 20; ++j) {
    int d = lane + 64 * j;
    qr[j] = (d < DTOK) ? qrow[d] : 0.f;
  }
  for (int m2 = wave; m2 < 80; m2 += 4) {
    const float* krow = qkv + (size_t)(b * NBOU + m2) * OQKV + DTOK;
    float a = 0.f;
#pragma unroll
    for (int j = 0; j < 20; ++j) {
      int d = lane + 64 * j;
      if (d < DTOK) a += qr[j] * krow[d];
    }
    a = wave_red_sum(a);
    if (lane == 0) p[m2] = a * (1.0f / 34.957116f);
  }
  __syncthreads();
  if (wave == 0) {
    float x0 = p[lane];
    float x1 = (lane < 16) ? p[64 + lane] : -INFINITY;
    float mx = fmaxf(x0, x1);
#pragma unroll
    for (int off = 32; off; off >>= 1) mx = fmaxf(mx, __shfl_xor(mx, off, 64));
    float e0 = expf(x0 - mx);
    float e1 = (lane < 16) ? expf(x1 - mx) : 0.f;
    float ssum = wave_red_sum(e0 + e1);
    p[lane] = e0 / ssum;
    if (lane < 16) p[64 + lane] = e1 / ssum;
  }
  __syncthreads();
  float acc[5] = {0, 0, 0, 0, 0};
  for (int m2 = 0; m2 < 80; ++m2) {
    float pm = p[m2];
    const float* vrow = qkv + (size_t)(b * NBOU + m2) * OQKV + 2 * DTOK;
#pragma unroll
    for (int i = 0; i < 5; ++i) {
      int d = tid + 256 * i;
      if (d < DTOK) acc[i] += pm * vrow[d];
    }
  }
#pragma unroll
  for (int i = 0; i < 5; ++i) {
    int d = tid + 256 * i;
    if (d < DTOK) attn_out[(size_t)blk * DTOK + d] = acc[i];
  }
}

extern "C" void kernel_launch(void* const* d_in, const int* in_sizes, int n_in,
                              void* d_out, int out_size, void* d_ws, size_t ws_size,
                              hipStream_t stream) {
  const float* f   = (const float*)d_in[0];
  const int*   pb  = (const int*)d_in[1];
  const float* lng = (const float*)d_in[2];
  const float* lnb = (const float*)d_in[3];
  const float* ipw = (const float*)d_in[4];
  const float* ipb = (const float*)d_in[5];
  const float* opw = (const float*)d_in[6];
  const float* opb = (const float*)d_in[7];
  const float* l1w = (const float*)d_in[8];
  const float* l1b = (const float*)d_in[9];
  const float* l2w = (const float*)d_in[10];
  const float* l2b = (const float*)d_in[11];
  const float* n1g = (const float*)d_in[12];
  const float* n1b = (const float*)d_in[13];
  const float* n2g = (const float*)d_in[14];
  const float* n2b = (const float*)d_in[15];
  const float* fcw = (const float*)d_in[16];
  const float* fcb = (const float*)d_in[17];
  int* outp = (int*)d_out;

  const int T1 = 39;   // ceil(1222/32)
  const int T2 = 64;   // 2048/32
  const int NT_IP = 58, NT_OP = 20, NT_L1 = 32, NT_L2 = 20;
  const int S_IP = 4, S_OP = 8, S_L1 = 6, S_L2 = 8;

  char* wsb = (char*)d_ws;
  auto alloc = [&](size_t bytes) -> char* {
    char* p = wsb;
    wsb += (bytes + 255) & ~(size_t)255;
    return p;
  };
  float* L0n  = (float*)alloc((size_t)2 * 224 * 224 * 1024 * 4);
  float* L1   = (float*)alloc((size_t)2 * 112 * 112 * 1024 * 4);
  float* L2   = (float*)alloc((size_t)2 * 56 * 56 * 1024 * 4);
  float* L3   = (float*)alloc((size_t)2 * 28 * 28 * 1024 * 4);
  float* pe   = (float*)alloc((size_t)NBOU * DTOK * 4);
  int*   bnd  = (int*)alloc(320 * 4);
  float* tokens = (float*)alloc((size_t)MM * DTOK * 4);
  float* qkvb   = (float*)alloc((size_t)MM * OQKV * 4);
  float* attnb  = (float*)alloc((size_t)MM * DTOK * 4);
  float* x1     = (float*)alloc((size_t)MM * DTOK * 4);
  float* hb     = (float*)alloc((size_t)MM * FFD * 4);
  short* ipWf = (short*)alloc((size_t)NT_IP * T1 * 6144 * 2);
  short* opWf = (short*)alloc((size_t)NT_OP * T1 * 6144 * 2);
  short* l1Wf = (short*)alloc((size_t)NT_L1 * T1 * 6144 * 2);
  short* l2Wf = (short*)alloc((size_t)NT_L2 * T2 * 6144 * 2);
  float* part = (float*)alloc((size_t)8 * MM * OQKV * 4);

  k_nhwc0<<<dim3(7, 224, 64), 256, 0, stream>>>(f, L0n);
  k_pool_nhwc<<<dim3(112, 112, 2), 256, 0, stream>>>(L0n, L1, 112);
  k_pool_nhwc<<<dim3(56, 56, 2), 256, 0, stream>>>(L1, L2, 56);
  k_pool_nhwc<<<dim3(28, 28, 2), 256, 0, stream>>>(L2, L3, 28);
  k_pe<<<NBOU, 256, 0, stream>>>(pe, bnd, pb);

  k_conv<<<NT_IP * T1, 256, 0, stream>>>(ipw, ipWf, OQKV, DTOK, T1);
  k_conv<<<NT_OP * T1, 256, 0, stream>>>(opw, opWf, DTOK, DTOK, T1);
  k_conv<<<NT_L1 * T1, 256, 0, stream>>>(l1w, l1Wf, FFD, DTOK, T1);
  k_conv<<<NT_L2 * T2, 256, 0, stream>>>(l2w, l2Wf, DTOK, FFD, T2);

  for (int it = 0; it < 6; ++it) {
    k_tok<<<160, 256, 0, stream>>>(L0n, L1, L2, L3, bnd, lng, lnb, pe, tokens);

    // in_proj -> qkvb
    k_mfma_s<<<dim3(NT_IP, 3, S_IP), 256, 0, stream>>>(tokens, ipWf, part, DTOK, T1, OQKV, S_IP);
    k_red<<<(MM * OQKV + 1023) / 1024, 256, 0, stream>>>(part, ipb, nullptr, qkvb, OQKV, S_IP, 0);

    k_attn<<<160, 256, 0, stream>>>(qkvb, attnb);

    // out_proj + tokens residual + norm1 -> x1
    k_mfma_s<<<dim3(NT_OP, 3, S_OP), 256, 0, stream>>>(attnb, opWf, part, DTOK, T1, DTOK, S_OP);
    k_redln<<<160, 256, 0, stream>>>(part, opb, tokens, n1g, n1b, x1, S_OP);

    // lin1 (relu) -> hb
    k_mfma_s<<<dim3(NT_L1, 3, S_L1), 256, 0, stream>>>(x1, l1Wf, part, DTOK, T1, FFD, S_L1);
    k_red<<<(MM * FFD + 1023) / 1024, 256, 0, stream>>>(part, l1b, nullptr, hb, FFD, S_L1, 1);

    // lin2 + x1 residual + norm2 + fc head
    k_mfma_s<<<dim3(NT_L2, 3, S_L2), 256, 0, stream>>>(hb, l2Wf, part, FFD, T2, DTOK, S_L2);
    k_redlnfc<<<160, 256, 0, stream>>>(part, l2b, x1, n2g, n2b, fcw, fcb, bnd, outp + it * 320, S_L2);
  }
}